// Round 1
// baseline (457.744 us; speedup 1.0000x reference)
//
#include <hip/hip_runtime.h>
#include <hip/hip_bf16.h>
#include <math.h>

typedef __attribute__((ext_vector_type(4))) float f32x4;
typedef __attribute__((ext_vector_type(8))) short bf16x8;
typedef __attribute__((ext_vector_type(4))) short short4v;

#define EPSN 1e-12f
#define TN 32
#define YP 644

__device__ inline short f2bf(float x) {
    union { float f; unsigned u; } v; v.f = x;
    unsigned r = v.u + 0x7fffu + ((v.u >> 16) & 1u);
    return (short)(r >> 16);
}

__device__ inline float wsum64(float v) {
#pragma unroll
    for (int m = 32; m > 0; m >>= 1) v += __shfl_xor(v, m);
    return v;
}

__device__ inline float sigm(float x) { return 1.0f / (1.0f + __expf(-x)); }

// ---- prep: W_f (256x256) + W_iou (384x256) -> bf16 fragment-linear B ----
// Blin element t*8+e : t = ((kb*40)+jb)*64 + lane ; j = jb*16+(lane&15),
// k = kb*32+(lane>>4)*8+e ; value = W[j][k]
__global__ void prep_B(const float* __restrict__ W_f, const float* __restrict__ W_iou,
                       short* __restrict__ Blin) {
    int t = blockIdx.x * 256 + threadIdx.x;
    if (t >= 8 * 40 * 64) return;
    int lane = t & 63;
    int jb = (t >> 6) % 40;
    int kb = (t >> 6) / 40;
    int j = jb * 16 + (lane & 15);
    int k = kb * 32 + ((lane >> 4) << 3);
    const float* src = (j < 256) ? (W_f + (size_t)j * 256 + k)
                                 : (W_iou + (size_t)(j - 256) * 256 + k);
    bf16x8 v;
#pragma unroll
    for (int e = 0; e < 8; ++e) v[e] = f2bf(src[e]);
    *(bf16x8*)(Blin + (size_t)t * 8) = v;
}

// ---- fused: gather -> norms -> bf16 MFMA GEMM (A:32x256, B:640x256^T) -> epilogue
__global__ __launch_bounds__(512, 2) void tree_fused(
    const float* __restrict__ h_src, const float* __restrict__ c_src,
    const float* __restrict__ iou, const int* __restrict__ child_idx,
    const float* __restrict__ b_f, const float* __restrict__ b_iou,
    const float* __restrict__ sc_iou_p, const float* __restrict__ sc_c_p,
    const short* __restrict__ Blin, float* __restrict__ out) {
    __shared__ short A_lds[TN * 256];     // bf16, rows of 512B, XOR-swizzled
    __shared__ float Yt[TN][YP];          // GEMM output staging (padded)
    __shared__ float c_lds[TN][256];      // gathered child c rows
    __shared__ float h_n2[TN], c0_n2[TN], iou_n2[TN];

    const int tid = threadIdx.x;
    const int wave = tid >> 6;
    const int lane = tid & 63;
    const int nbase = blockIdx.x * TN;

    // ---------- gather h/c + all input norms ----------
#pragma unroll
    for (int r = 0; r < 4; ++r) {
        const int nd = wave + 8 * r;          // 0..31 (one node per wave-iter)
        const int node = nbase + nd;
        const int child = lane >> 5;          // 0 or 1
        const int seg = lane & 31;            // float4 slot within the 128-row
        const int cix = child_idx[(size_t)node * 2 + child];
        const f32x4 hv = *(const f32x4*)(h_src + (size_t)cix * 128 + seg * 4);
        const f32x4 cv = *(const f32x4*)(c_src + (size_t)cix * 128 + seg * 4);
        float hss = hv.x * hv.x + hv.y * hv.y + hv.z * hv.z + hv.w * hv.w;
        float css = (child == 0) ? (cv.x * cv.x + cv.y * cv.y + cv.z * cv.z + cv.w * cv.w) : 0.0f;
        float iss = 0.0f;
#pragma unroll
        for (int q = 0; q < 6; ++q) {
            float v = iou[(size_t)node * 384 + q * 64 + lane];
            iss += v * v;
        }
        // stage A tile (bf16, swizzled)
        short4v a4;
        a4.x = f2bf(hv.x); a4.y = f2bf(hv.y); a4.z = f2bf(hv.z); a4.w = f2bf(hv.w);
        const int byte_in_row = child * 256 + seg * 8;
        const int swz = byte_in_row ^ ((nd & 7) << 4);
        *(short4v*)((char*)A_lds + nd * 512 + swz) = a4;
        // stage c tile (fp32, linear)
        *(f32x4*)&c_lds[nd][child * 128 + seg * 4] = cv;
        // wave reductions
        hss = wsum64(hss);
        css = wsum64(css);
        iss = wsum64(iss);
        if (lane == 0) { h_n2[nd] = hss; c0_n2[nd] = css; iou_n2[nd] = iss; }
    }
    __syncthreads();

    // ---------- MFMA main: Y[32][640] = A * B^T ----------
    f32x4 acc[2][5];
#pragma unroll
    for (int m = 0; m < 2; ++m)
#pragma unroll
        for (int j = 0; j < 5; ++j) acc[m][j] = (f32x4){0.f, 0.f, 0.f, 0.f};

    const int arow = lane & 15;
    const int kgrp = lane >> 4;   // 0..3
#pragma unroll
    for (int kb = 0; kb < 8; ++kb) {
        bf16x8 af[2];
#pragma unroll
        for (int m = 0; m < 2; ++m) {
            const int row = arow + m * 16;
            const int bofs = (kb * 64 + kgrp * 16) ^ ((row & 7) << 4);
            af[m] = *(const bf16x8*)((const char*)A_lds + row * 512 + bofs);
        }
#pragma unroll
        for (int jj = 0; jj < 5; ++jj) {
            const int jb = wave * 5 + jj;
            const bf16x8 bfr = *(const bf16x8*)(Blin + ((size_t)(kb * 40 + jb) * 64 + lane) * 8);
            acc[0][jj] = __builtin_amdgcn_mfma_f32_16x16x32_bf16(af[0], bfr, acc[0][jj], 0, 0, 0);
            acc[1][jj] = __builtin_amdgcn_mfma_f32_16x16x32_bf16(af[1], bfr, acc[1][jj], 0, 0, 0);
        }
    }
    // spill Y to LDS: C/D layout col=lane&15, row=(lane>>4)*4+reg
#pragma unroll
    for (int m = 0; m < 2; ++m)
#pragma unroll
        for (int jj = 0; jj < 5; ++jj) {
            const int col = (wave * 5 + jj) * 16 + (lane & 15);
            const int r0 = m * 16 + (lane >> 4) * 4;
#pragma unroll
            for (int r = 0; r < 4; ++r) Yt[r0 + r][col] = acc[m][jj][r];
        }
    __syncthreads();

    // ---------- epilogue: 16 threads per node ----------
    const float sc_iou = sc_iou_p[0];
    const float sc_c = sc_c_p[0];
    const int nd = tid >> 4;        // 0..31
    const int hseg = tid & 15;      // 0..15
    const int h0 = hseg * 8;
    const int node = nbase + nd;

    const float s_iou = sc_iou * sqrtf(iou_n2[nd]) / fmaxf(sqrtf(h_n2[nd]), EPSN);

    float cs[8];
    float csn2 = 0.0f;
#pragma unroll
    for (int e = 0; e < 8; ++e) {
        const int h = h0 + e;
        const float f0 = sigm(Yt[nd][h] + b_f[h]);
        const float f1 = sigm(Yt[nd][128 + h] + b_f[128 + h]);
        const float v = f0 * c_lds[nd][h] + f1 * c_lds[nd][128 + h];
        cs[e] = v;
        csn2 += v * v;
    }
    // 16-lane butterfly: all 16 threads of this node live in one wave
    csn2 += __shfl_xor(csn2, 1);
    csn2 += __shfl_xor(csn2, 2);
    csn2 += __shfl_xor(csn2, 4);
    csn2 += __shfl_xor(csn2, 8);
    const float rs = sc_c * sqrtf(c0_n2[nd]) / fmaxf(sqrtf(csn2), EPSN);

    f32x4 outh[2], outc[2];
#pragma unroll
    for (int e = 0; e < 8; ++e) {
        const int h = h0 + e;
        const float iv = Yt[nd][256 + h] * s_iou + b_iou[h];
        const float ov = Yt[nd][384 + h] * s_iou + b_iou[128 + h];
        const float uv = Yt[nd][512 + h] * s_iou + b_iou[256 + h];
        const float cval = sigm(iv) * tanhf(uv) + cs[e] * rs;
        const float hval = sigm(ov) * tanhf(cval);
        ((float*)outh)[e] = hval;
        ((float*)outc)[e] = cval;
    }
    *(f32x4*)(out + (size_t)node * 256 + h0) = outh[0];
    *(f32x4*)(out + (size_t)node * 256 + h0 + 4) = outh[1];
    *(f32x4*)(out + (size_t)node * 256 + 128 + h0) = outc[0];
    *(f32x4*)(out + (size_t)node * 256 + 128 + h0 + 4) = outc[1];
}

extern "C" void kernel_launch(void* const* d_in, const int* in_sizes, int n_in,
                              void* d_out, int out_size, void* d_ws, size_t ws_size,
                              hipStream_t stream) {
    const float* h_src = (const float*)d_in[0];
    const float* c_src = (const float*)d_in[1];
    const float* iou = (const float*)d_in[2];
    const int* cidx = (const int*)d_in[3];
    const float* W_f = (const float*)d_in[4];
    const float* b_f = (const float*)d_in[5];
    const float* W_iou = (const float*)d_in[6];
    const float* b_iou = (const float*)d_in[7];
    const float* s_iou = (const float*)d_in[8];
    const float* s_c = (const float*)d_in[9];
    float* out = (float*)d_out;
    short* Blin = (short*)d_ws;   // 640*256 bf16 = 320 KB elements -> 640 KB

    const int N = in_sizes[3] / 2;          // 200000
    hipLaunchKernelGGL(prep_B, dim3(80), dim3(256), 0, stream, W_f, W_iou, Blin);
    hipLaunchKernelGGL(tree_fused, dim3(N / TN), dim3(512), 0, stream,
                       h_src, c_src, iou, cidx, b_f, b_iou, s_iou, s_c, Blin, out);
}

// Round 2
// 307.441 us; speedup vs baseline: 1.4889x; 1.4889x over previous
//
#include <hip/hip_runtime.h>
#include <math.h>

typedef __attribute__((ext_vector_type(4))) float f32x4;
typedef __attribute__((ext_vector_type(8))) short bf16x8;
typedef __attribute__((ext_vector_type(4))) short short4v;

#define EPSN 1e-12f
#define TN 32
#define YP 648   // Yt row stride in shorts (1296 B, 16B-aligned)

__device__ inline short f2bf(float x) {
    union { float f; unsigned u; } v; v.f = x;
    unsigned r = v.u + 0x7fffu + ((v.u >> 16) & 1u);
    return (short)(r >> 16);
}
__device__ inline float bf2f(short s) {
    union { unsigned u; float f; } v;
    v.u = ((unsigned)(unsigned short)s) << 16;
    return v.f;
}
__device__ inline float wsum64(float v) {
#pragma unroll
    for (int m = 32; m > 0; m >>= 1) v += __shfl_xor(v, m);
    return v;
}
__device__ inline float wsum16(float v) {
    v += __shfl_xor(v, 1);
    v += __shfl_xor(v, 2);
    v += __shfl_xor(v, 4);
    v += __shfl_xor(v, 8);
    return v;
}
__device__ inline float sigm(float x) { return 1.0f / (1.0f + __expf(-x)); }
__device__ inline float tanh_fast(float x) {
    float a = fabsf(x);
    float e = __expf(2.0f * a);
    float t = 1.0f - 2.0f / (e + 1.0f);
    return copysignf(t, x);
}

// ---- prep: W_f (256x256) + W_iou (384x256) -> bf16 fragment-linear B ----
__global__ void prep_B(const float* __restrict__ W_f, const float* __restrict__ W_iou,
                       short* __restrict__ Blin) {
    int t = blockIdx.x * 256 + threadIdx.x;
    if (t >= 8 * 40 * 64) return;
    int lane = t & 63;
    int jb = (t >> 6) % 40;
    int kb = (t >> 6) / 40;
    int j = jb * 16 + (lane & 15);
    int k = kb * 32 + ((lane >> 4) << 3);
    const float* src = (j < 256) ? (W_f + (size_t)j * 256 + k)
                                 : (W_iou + (size_t)(j - 256) * 256 + k);
    bf16x8 v;
#pragma unroll
    for (int e = 0; e < 8; ++e) v[e] = f2bf(src[e]);
    *(bf16x8*)(Blin + (size_t)t * 8) = v;
}

// ---- fused: gather -> bf16 MFMA GEMM (A:32x256, B:640x256^T) -> epilogue
__global__ __launch_bounds__(512, 4) void tree_fused(
    const float* __restrict__ h_src, const float* __restrict__ c_src,
    const float* __restrict__ iou, const int* __restrict__ child_idx,
    const float* __restrict__ b_f, const float* __restrict__ b_iou,
    const float* __restrict__ sc_iou_p, const float* __restrict__ sc_c_p,
    const short* __restrict__ Blin, float* __restrict__ out) {
    __shared__ short A_lds[TN * 256];   // bf16, 512B rows, XOR-swizzled
    __shared__ short Yt[TN][YP];        // bf16 GEMM output staging
    __shared__ float h_n2[TN];

    const int tid = threadIdx.x;
    const int wave = tid >> 6;
    const int lane = tid & 63;
    const int nbase = blockIdx.x * TN;

    // ---------- gather h + h-norm (one node per (wave,r)) ----------
    {
        const int child = lane >> 5;
        const int seg = lane & 31;
        int cix[4];
#pragma unroll
        for (int r = 0; r < 4; ++r)
            cix[r] = child_idx[(size_t)(nbase + wave + 8 * r) * 2 + child];
        f32x4 hv[4];
#pragma unroll
        for (int r = 0; r < 4; ++r)
            hv[r] = *(const f32x4*)(h_src + (size_t)cix[r] * 128 + seg * 4);
#pragma unroll
        for (int r = 0; r < 4; ++r) {
            const int nd = wave + 8 * r;
            short4v a4;
            a4.x = f2bf(hv[r].x); a4.y = f2bf(hv[r].y);
            a4.z = f2bf(hv[r].z); a4.w = f2bf(hv[r].w);
            const int swz = (lane * 8) ^ ((nd & 7) << 4);
            *(short4v*)((char*)A_lds + nd * 512 + swz) = a4;
            float hss = hv[r].x * hv[r].x + hv[r].y * hv[r].y
                      + hv[r].z * hv[r].z + hv[r].w * hv[r].w;
            hss = wsum64(hss);
            if (lane == 0) h_n2[nd] = hss;
        }
    }
    __syncthreads();

    // ---------- MFMA main: Y[32][640] = A * B^T ----------
    f32x4 acc[2][5];
#pragma unroll
    for (int m = 0; m < 2; ++m)
#pragma unroll
        for (int j = 0; j < 5; ++j) acc[m][j] = (f32x4){0.f, 0.f, 0.f, 0.f};

    const int arow = lane & 15;
    const int kgrp = lane >> 4;
#pragma unroll
    for (int kb = 0; kb < 8; ++kb) {
        bf16x8 af[2];
#pragma unroll
        for (int m = 0; m < 2; ++m) {
            const int row = arow + m * 16;
            const int bofs = (kb * 64 + kgrp * 16) ^ ((row & 7) << 4);
            af[m] = *(const bf16x8*)((const char*)A_lds + row * 512 + bofs);
        }
#pragma unroll
        for (int jj = 0; jj < 5; ++jj) {
            const int jb = wave * 5 + jj;
            const bf16x8 bfr = *(const bf16x8*)(Blin + ((size_t)(kb * 40 + jb) * 64 + lane) * 8);
            acc[0][jj] = __builtin_amdgcn_mfma_f32_16x16x32_bf16(af[0], bfr, acc[0][jj], 0, 0, 0);
            acc[1][jj] = __builtin_amdgcn_mfma_f32_16x16x32_bf16(af[1], bfr, acc[1][jj], 0, 0, 0);
        }
    }
    // spill Y (bf16): C/D layout col=lane&15, row=(lane>>4)*4+reg
#pragma unroll
    for (int m = 0; m < 2; ++m)
#pragma unroll
        for (int jj = 0; jj < 5; ++jj) {
            const int col = (wave * 5 + jj) * 16 + (lane & 15);
            const int r0 = m * 16 + (lane >> 4) * 4;
#pragma unroll
            for (int r = 0; r < 4; ++r) Yt[r0 + r][col] = f2bf(acc[m][jj][r]);
        }
    __syncthreads();

    // ---------- epilogue: 16 threads per node ----------
    const float sc_iou = sc_iou_p[0];
    const float sc_c = sc_c_p[0];
    const int nd = tid >> 4;
    const int hseg = tid & 15;
    const int h0 = hseg * 8;
    const int node = nbase + nd;

    // iou norm (contiguous 256B per node per instruction)
    float iss = 0.f;
#pragma unroll
    for (int q = 0; q < 6; ++q) {
        f32x4 v = *(const f32x4*)(iou + (size_t)node * 384 + q * 64 + hseg * 4);
        iss += v.x * v.x + v.y * v.y + v.z * v.z + v.w * v.w;
    }
    iss = wsum16(iss);

    // child c rows (read once, here)
    const int2 cc = *(const int2*)(child_idx + (size_t)node * 2);
    float c0v[8], c1v[8];
    *(f32x4*)&c0v[0] = *(const f32x4*)(c_src + (size_t)cc.x * 128 + h0);
    *(f32x4*)&c0v[4] = *(const f32x4*)(c_src + (size_t)cc.x * 128 + h0 + 4);
    *(f32x4*)&c1v[0] = *(const f32x4*)(c_src + (size_t)cc.y * 128 + h0);
    *(f32x4*)&c1v[4] = *(const f32x4*)(c_src + (size_t)cc.y * 128 + h0 + 4);
    float c0n2 = 0.f;
#pragma unroll
    for (int e = 0; e < 8; ++e) c0n2 += c0v[e] * c0v[e];
    c0n2 = wsum16(c0n2);

    // Y slices (bf16 from LDS)
    const bf16x8 yf0 = *(const bf16x8*)&Yt[nd][h0];
    const bf16x8 yf1 = *(const bf16x8*)&Yt[nd][128 + h0];
    const bf16x8 yi  = *(const bf16x8*)&Yt[nd][256 + h0];
    const bf16x8 yo  = *(const bf16x8*)&Yt[nd][384 + h0];
    const bf16x8 yu  = *(const bf16x8*)&Yt[nd][512 + h0];

    float bfv[16];
    *(f32x4*)&bfv[0]  = *(const f32x4*)(b_f + h0);
    *(f32x4*)&bfv[4]  = *(const f32x4*)(b_f + h0 + 4);
    *(f32x4*)&bfv[8]  = *(const f32x4*)(b_f + 128 + h0);
    *(f32x4*)&bfv[12] = *(const f32x4*)(b_f + 128 + h0 + 4);

    float cs[8];
    float csn2 = 0.f;
#pragma unroll
    for (int e = 0; e < 8; ++e) {
        const float f0 = sigm(bf2f(yf0[e]) + bfv[e]);
        const float f1 = sigm(bf2f(yf1[e]) + bfv[8 + e]);
        const float v = f0 * c0v[e] + f1 * c1v[e];
        cs[e] = v;
        csn2 += v * v;
    }
    csn2 = wsum16(csn2);

    const float s_iou = sc_iou * sqrtf(iss) / fmaxf(sqrtf(h_n2[nd]), EPSN);
    const float rs = sc_c * sqrtf(c0n2) / fmaxf(sqrtf(csn2), EPSN);

    float biv[24];
    *(f32x4*)&biv[0]  = *(const f32x4*)(b_iou + h0);
    *(f32x4*)&biv[4]  = *(const f32x4*)(b_iou + h0 + 4);
    *(f32x4*)&biv[8]  = *(const f32x4*)(b_iou + 128 + h0);
    *(f32x4*)&biv[12] = *(const f32x4*)(b_iou + 128 + h0 + 4);
    *(f32x4*)&biv[16] = *(const f32x4*)(b_iou + 256 + h0);
    *(f32x4*)&biv[20] = *(const f32x4*)(b_iou + 256 + h0 + 4);

    f32x4 outh[2], outc[2];
#pragma unroll
    for (int e = 0; e < 8; ++e) {
        const float iv = bf2f(yi[e]) * s_iou + biv[e];
        const float ov = bf2f(yo[e]) * s_iou + biv[8 + e];
        const float uv = bf2f(yu[e]) * s_iou + biv[16 + e];
        const float cval = sigm(iv) * tanh_fast(uv) + cs[e] * rs;
        const float hval = sigm(ov) * tanh_fast(cval);
        ((float*)outh)[e] = hval;
        ((float*)outc)[e] = cval;
    }
    *(f32x4*)(out + (size_t)node * 256 + h0) = outh[0];
    *(f32x4*)(out + (size_t)node * 256 + h0 + 4) = outh[1];
    *(f32x4*)(out + (size_t)node * 256 + 128 + h0) = outc[0];
    *(f32x4*)(out + (size_t)node * 256 + 128 + h0 + 4) = outc[1];
}

extern "C" void kernel_launch(void* const* d_in, const int* in_sizes, int n_in,
                              void* d_out, int out_size, void* d_ws, size_t ws_size,
                              hipStream_t stream) {
    const float* h_src = (const float*)d_in[0];
    const float* c_src = (const float*)d_in[1];
    const float* iou = (const float*)d_in[2];
    const int* cidx = (const int*)d_in[3];
    const float* W_f = (const float*)d_in[4];
    const float* b_f = (const float*)d_in[5];
    const float* W_iou = (const float*)d_in[6];
    const float* b_iou = (const float*)d_in[7];
    const float* s_iou = (const float*)d_in[8];
    const float* s_c = (const float*)d_in[9];
    float* out = (float*)d_out;
    short* Blin = (short*)d_ws;

    const int N = in_sizes[3] / 2;  // 200000
    hipLaunchKernelGGL(prep_B, dim3(80), dim3(256), 0, stream, W_f, W_iou, Blin);
    hipLaunchKernelGGL(tree_fused, dim3(N / TN), dim3(512), 0, stream,
                       h_src, c_src, iou, cidx, b_f, b_iou, s_iou, s_c, Blin, out);
}

// Round 3
// 275.556 us; speedup vs baseline: 1.6612x; 1.1157x over previous
//
#include <hip/hip_runtime.h>
#include <math.h>

typedef __attribute__((ext_vector_type(4))) float f32x4;
typedef __attribute__((ext_vector_type(8))) short bf16x8;
typedef __attribute__((ext_vector_type(4))) short short4v;

#define EPSN 1e-12f
#define TN 32
#define YS 640   // Yt row stride in shorts (XOR-swizzled, no pad)

__device__ inline short f2bf(float x) {
    union { float f; unsigned u; } v; v.f = x;
    unsigned r = v.u + 0x7fffu + ((v.u >> 16) & 1u);
    return (short)(r >> 16);
}
__device__ inline float bf2f(short s) {
    union { unsigned u; float f; } v;
    v.u = ((unsigned)(unsigned short)s) << 16;
    return v.f;
}
__device__ inline float wsum64(float v) {
#pragma unroll
    for (int m = 32; m > 0; m >>= 1) v += __shfl_xor(v, m);
    return v;
}
__device__ inline float wsum16(float v) {
    v += __shfl_xor(v, 1);
    v += __shfl_xor(v, 2);
    v += __shfl_xor(v, 4);
    v += __shfl_xor(v, 8);
    return v;
}
__device__ inline float sigm(float x) { return 1.0f / (1.0f + __expf(-x)); }
__device__ inline float tanh_fast(float x) {
    float a = fabsf(x);
    float e = __expf(2.0f * a);
    float t = 1.0f - 2.0f / (e + 1.0f);
    return copysignf(t, x);
}

// ---- prep: W_f (256x256) + W_iou (384x256) -> bf16 fragment-linear B ----
__global__ void prep_B(const float* __restrict__ W_f, const float* __restrict__ W_iou,
                       short* __restrict__ Blin) {
    int t = blockIdx.x * 256 + threadIdx.x;
    if (t >= 8 * 40 * 64) return;
    int lane = t & 63;
    int jb = (t >> 6) % 40;
    int kb = (t >> 6) / 40;
    int j = jb * 16 + (lane & 15);
    int k = kb * 32 + ((lane >> 4) << 3);
    const float* src = (j < 256) ? (W_f + (size_t)j * 256 + k)
                                 : (W_iou + (size_t)(j - 256) * 256 + k);
    bf16x8 v;
#pragma unroll
    for (int e = 0; e < 8; ++e) v[e] = f2bf(src[e]);
    *(bf16x8*)(Blin + (size_t)t * 8) = v;
}

// ---- fused: gather -> bf16 MFMA GEMM (A:32x256, B:640x256^T) -> epilogue
__global__ __launch_bounds__(512, 6) void tree_fused(
    const float* __restrict__ h_src, const float* __restrict__ c_src,
    const float* __restrict__ iou, const int* __restrict__ child_idx,
    const float* __restrict__ b_f, const float* __restrict__ b_iou,
    const float* __restrict__ sc_iou_p, const float* __restrict__ sc_c_p,
    const short* __restrict__ Blin, float* __restrict__ out) {
    // Union: phases 1-2 use U as A (32 rows x 512B, XOR-swizzled bf16);
    // phases 3-4 use U as Yt (32 rows x 640 shorts, XOR-swizzled bf16).
    __shared__ short U[TN * YS];        // 40,960 B
    __shared__ float h_n2[TN], iou_n2[TN];
    __shared__ int cc_lds[TN][2];

    const int tid = threadIdx.x;
    const int wave = tid >> 6;
    const int lane = tid & 63;
    const int nbase = blockIdx.x * TN;

    // ---------- phase 1: gather h -> A, h-norm, iou-norm, stash child idx ----------
    {
        const int child = lane >> 5;
        const int seg = lane & 31;
        int cix[4];
#pragma unroll
        for (int r = 0; r < 4; ++r)
            cix[r] = child_idx[(size_t)(nbase + wave + 8 * r) * 2 + child];
        f32x4 hv[4];
#pragma unroll
        for (int r = 0; r < 4; ++r)
            hv[r] = *(const f32x4*)(h_src + (size_t)cix[r] * 128 + seg * 4);
#pragma unroll
        for (int r = 0; r < 4; ++r) {
            const int nd = wave + 8 * r;
            const int node = nbase + nd;
            short4v a4;
            a4.x = f2bf(hv[r].x); a4.y = f2bf(hv[r].y);
            a4.z = f2bf(hv[r].z); a4.w = f2bf(hv[r].w);
            const int swz = (lane * 8) ^ ((nd & 7) << 4);
            *(short4v*)((char*)U + nd * 512 + swz) = a4;
            if (lane == 0) cc_lds[nd][0] = cix[r];
            if (lane == 32) cc_lds[nd][1] = cix[r];
            float hss = hv[r].x * hv[r].x + hv[r].y * hv[r].y
                      + hv[r].z * hv[r].z + hv[r].w * hv[r].w;
            float iss = 0.f;
#pragma unroll
            for (int q = 0; q < 6; ++q) {
                float v = iou[(size_t)node * 384 + q * 64 + lane];
                iss += v * v;
            }
            hss = wsum64(hss);
            iss = wsum64(iss);
            if (lane == 0) { h_n2[nd] = hss; iou_n2[nd] = iss; }
        }
    }
    __syncthreads();

    // ---------- phase 2: MFMA main, Y[32][640] = A * B^T ----------
    f32x4 acc[2][5];
#pragma unroll
    for (int m = 0; m < 2; ++m)
#pragma unroll
        for (int j = 0; j < 5; ++j) acc[m][j] = (f32x4){0.f, 0.f, 0.f, 0.f};

    const int arow = lane & 15;
    const int kgrp = lane >> 4;
#pragma unroll
    for (int kb = 0; kb < 8; ++kb) {
        bf16x8 af[2];
#pragma unroll
        for (int m = 0; m < 2; ++m) {
            const int row = arow + m * 16;
            const int bofs = (kb * 64 + kgrp * 16) ^ ((row & 7) << 4);
            af[m] = *(const bf16x8*)((const char*)U + row * 512 + bofs);
        }
#pragma unroll
        for (int jj = 0; jj < 5; ++jj) {
            const int jb = wave * 5 + jj;
            const bf16x8 bfr = *(const bf16x8*)(Blin + ((size_t)(kb * 40 + jb) * 64 + lane) * 8);
            acc[0][jj] = __builtin_amdgcn_mfma_f32_16x16x32_bf16(af[0], bfr, acc[0][jj], 0, 0, 0);
            acc[1][jj] = __builtin_amdgcn_mfma_f32_16x16x32_bf16(af[1], bfr, acc[1][jj], 0, 0, 0);
        }
    }
    __syncthreads();   // drain all A reads before Yt overwrites U

    // ---------- phase 3: spill Y (bf16, XOR-swizzled) ----------
    // C/D layout: col = lane&15 (+16*jb), row = (lane>>4)*4 + r (+16*m)
#pragma unroll
    for (int m = 0; m < 2; ++m)
#pragma unroll
        for (int jj = 0; jj < 5; ++jj) {
            const int col = (wave * 5 + jj) * 16 + (lane & 15);
            const int r0 = m * 16 + (lane >> 4) * 4;
#pragma unroll
            for (int r = 0; r < 4; ++r) {
                const int row = r0 + r;
                U[row * YS + (col ^ (((row >> 2) & 3) << 4))] = f2bf(acc[m][jj][r]);
            }
        }
    __syncthreads();

    // ---------- phase 4: epilogue, 16 threads per node ----------
    const float sc_iou = sc_iou_p[0];
    const float sc_c = sc_c_p[0];
    const int nd = tid >> 4;
    const int hseg = tid & 15;
    const int h0 = hseg * 8;
    const int node = nbase + nd;

    // child c rows (indices from LDS -> no dependent global idx load)
    const int c0i = cc_lds[nd][0];
    const int c1i = cc_lds[nd][1];
    float c0v[8], c1v[8];
    *(f32x4*)&c0v[0] = *(const f32x4*)(c_src + (size_t)c0i * 128 + h0);
    *(f32x4*)&c0v[4] = *(const f32x4*)(c_src + (size_t)c0i * 128 + h0 + 4);
    *(f32x4*)&c1v[0] = *(const f32x4*)(c_src + (size_t)c1i * 128 + h0);
    *(f32x4*)&c1v[4] = *(const f32x4*)(c_src + (size_t)c1i * 128 + h0 + 4);

    float bfv[16];
    *(f32x4*)&bfv[0]  = *(const f32x4*)(b_f + h0);
    *(f32x4*)&bfv[4]  = *(const f32x4*)(b_f + h0 + 4);
    *(f32x4*)&bfv[8]  = *(const f32x4*)(b_f + 128 + h0);
    *(f32x4*)&bfv[12] = *(const f32x4*)(b_f + 128 + h0 + 4);

    const int swz = ((nd >> 2) & 3) << 4;
    const bf16x8 yf0 = *(const bf16x8*)&U[nd * YS + (h0 ^ swz)];
    const bf16x8 yf1 = *(const bf16x8*)&U[nd * YS + ((128 + h0) ^ swz)];
    const bf16x8 yi  = *(const bf16x8*)&U[nd * YS + ((256 + h0) ^ swz)];
    const bf16x8 yo  = *(const bf16x8*)&U[nd * YS + ((384 + h0) ^ swz)];
    const bf16x8 yu  = *(const bf16x8*)&U[nd * YS + ((512 + h0) ^ swz)];

    float c0n2 = 0.f;
#pragma unroll
    for (int e = 0; e < 8; ++e) c0n2 += c0v[e] * c0v[e];
    c0n2 = wsum16(c0n2);

    float cs[8];
    float csn2 = 0.f;
#pragma unroll
    for (int e = 0; e < 8; ++e) {
        const float f0 = sigm(bf2f(yf0[e]) + bfv[e]);
        const float f1 = sigm(bf2f(yf1[e]) + bfv[8 + e]);
        const float v = f0 * c0v[e] + f1 * c1v[e];
        cs[e] = v;
        csn2 += v * v;
    }
    csn2 = wsum16(csn2);

    const float s_iou = sc_iou * sqrtf(iou_n2[nd]) / fmaxf(sqrtf(h_n2[nd]), EPSN);
    const float rs = sc_c * sqrtf(c0n2) / fmaxf(sqrtf(csn2), EPSN);

    float biv[24];
    *(f32x4*)&biv[0]  = *(const f32x4*)(b_iou + h0);
    *(f32x4*)&biv[4]  = *(const f32x4*)(b_iou + h0 + 4);
    *(f32x4*)&biv[8]  = *(const f32x4*)(b_iou + 128 + h0);
    *(f32x4*)&biv[12] = *(const f32x4*)(b_iou + 128 + h0 + 4);
    *(f32x4*)&biv[16] = *(const f32x4*)(b_iou + 256 + h0);
    *(f32x4*)&biv[20] = *(const f32x4*)(b_iou + 256 + h0 + 4);

    f32x4 outh[2], outc[2];
#pragma unroll
    for (int e = 0; e < 8; ++e) {
        const float iv = bf2f(yi[e]) * s_iou + biv[e];
        const float ov = bf2f(yo[e]) * s_iou + biv[8 + e];
        const float uv = bf2f(yu[e]) * s_iou + biv[16 + e];
        const float cval = sigm(iv) * tanh_fast(uv) + cs[e] * rs;
        const float hval = sigm(ov) * tanh_fast(cval);
        ((float*)outh)[e] = hval;
        ((float*)outc)[e] = cval;
    }
    *(f32x4*)(out + (size_t)node * 256 + h0) = outh[0];
    *(f32x4*)(out + (size_t)node * 256 + h0 + 4) = outh[1];
    *(f32x4*)(out + (size_t)node * 256 + 128 + h0) = outc[0];
    *(f32x4*)(out + (size_t)node * 256 + 128 + h0 + 4) = outc[1];
}

extern "C" void kernel_launch(void* const* d_in, const int* in_sizes, int n_in,
                              void* d_out, int out_size, void* d_ws, size_t ws_size,
                              hipStream_t stream) {
    const float* h_src = (const float*)d_in[0];
    const float* c_src = (const float*)d_in[1];
    const float* iou = (const float*)d_in[2];
    const int* cidx = (const int*)d_in[3];
    const float* W_f = (const float*)d_in[4];
    const float* b_f = (const float*)d_in[5];
    const float* W_iou = (const float*)d_in[6];
    const float* b_iou = (const float*)d_in[7];
    const float* s_iou = (const float*)d_in[8];
    const float* s_c = (const float*)d_in[9];
    float* out = (float*)d_out;
    short* Blin = (short*)d_ws;

    const int N = in_sizes[3] / 2;  // 200000
    hipLaunchKernelGGL(prep_B, dim3(80), dim3(256), 0, stream, W_f, W_iou, Blin);
    hipLaunchKernelGGL(tree_fused, dim3(N / TN), dim3(512), 0, stream,
                       h_src, c_src, iou, cidx, b_f, b_iou, s_iou, s_c, Blin, out);
}